// Round 4
// baseline (644.514 us; speedup 1.0000x reference)
//
#include <hip/hip_runtime.h>
#include <hip/hip_bf16.h>

// Problem constants
#define B_  16
#define N_  512
#define M_  16
#define H_  8
#define D_  128
#define BN_ 8192   // B_*N_
#define RPB 4      // nodes (b,n) per block

static __device__ __forceinline__ float bf2f(__hip_bfloat16 x) { return __bfloat162float(x); }

// Load/store policy: interpret float tensors as f32 or bf16.
template <bool F32>
struct Pol {
    static __device__ __forceinline__ float ld(const void* p, int i) {
        if constexpr (F32) return ((const float*)p)[i];
        else               return bf2f(((const __hip_bfloat16*)p)[i]);
    }
    static __device__ __forceinline__ void st(void* p, int i, float v) {
        if constexpr (F32) ((float*)p)[i] = v;
        else               ((__hip_bfloat16*)p)[i] = __float2bfloat16(v);
    }
};

struct Smem {
    float hs[RPB][128];
    float wsrc[8][128];
    float wdst[8][128];
    float ssrc[RPB][8];
    float attn[RPB][16][8];
    float Z[RPB][8][128];
    float agg[RPB][1024];
    float yln[RPB][128];
    float ts[RPB][128];
    float us[RPB][256];
    float ys[RPB][128];
    int   nls[RPB][16];
    int   adjs[RPB][16];
};

template <bool F32>
static __device__ __forceinline__ void gat_body(
        Smem& s,
        const void* __restrict__ h,
        const int*  __restrict__ adj,
        const int*  __restrict__ n_list,
        const void* __restrict__ W,
        const void* __restrict__ a_src,
        const void* __restrict__ a_dst,
        const void* __restrict__ Wo,
        const void* __restrict__ g1,
        const void* __restrict__ bb1,
        const void* __restrict__ w1,
        const void* __restrict__ fb1,
        const void* __restrict__ w2,
        const void* __restrict__ fb2,
        const void* __restrict__ g2,
        const void* __restrict__ bb2,
        void* __restrict__ out) {
    using P = Pol<F32>;
    const int t   = threadIdx.x;
    const int bn0 = blockIdx.x * RPB;
    const int b   = bn0 >> 9;             // 512 nodes per batch

    // P0: wsrc[h][d] = sum_e W[h][d][e]*a_src[h][e]; likewise wdst.
    for (int i = t; i < 2048; i += 256) {
        const int which = i >> 10;
        const int hh = (i >> 7) & 7;
        const int d  = i & 127;
        const int wbase = hh * (D_ * D_) + d * 128;
        const void* av = which ? a_dst : a_src;
        float acc = 0.f;
        #pragma unroll 8
        for (int e = 0; e < 128; ++e) acc += P::ld(W, wbase + e) * P::ld(av, hh * 128 + e);
        if (which) s.wdst[hh][d] = acc; else s.wsrc[hh][d] = acc;
    }

    // P1: self rows + neighbor lists
    for (int i = t; i < RPB * 128; i += 256)
        s.hs[i >> 7][i & 127] = P::ld(h, (bn0 + (i >> 7)) * 128 + (i & 127));
    if (t < RPB * 16) {
        const int r = t >> 4, m = t & 15;
        s.nls[r][m]  = n_list[(bn0 + r) * M_ + m] & (N_ - 1);
        s.adjs[r][m] = adj[(bn0 + r) * M_ + m];
    }
    __syncthreads();

    // P2a: s_src[r][h] = hs[r]·wsrc[h]
    if (t < RPB * 8) {
        const int r = t >> 3, hh = t & 7;
        float acc = 0.f;
        #pragma unroll 8
        for (int d = 0; d < 128; ++d) acc += s.hs[r][d] * s.wsrc[hh][d];
        s.ssrc[r][hh] = acc;
    }
    __syncthreads();

    // P2b: scores = leaky(s_src + h[nl]·wdst), then mask
    for (int i = t; i < RPB * 16 * 8; i += 256) {
        const int r  = i >> 7;
        const int m  = (i >> 3) & 15;
        const int hh = i & 7;
        const int hbase = (b * N_ + s.nls[r][m]) * 128;
        float acc = 0.f;
        #pragma unroll 8
        for (int d = 0; d < 128; ++d) acc += P::ld(h, hbase + d) * s.wdst[hh][d];
        float sc = s.ssrc[r][hh] + acc;
        sc = sc > 0.f ? sc : 0.2f * sc;       // leaky_relu BEFORE mask (ref order)
        if (s.adjs[r][m] == 0) sc = -1e9f;
        s.attn[r][m][hh] = sc;
    }
    __syncthreads();

    // P3: softmax over m
    if (t < RPB * 8) {
        const int r = t >> 3, hh = t & 7;
        float mx = -3.4e38f;
        #pragma unroll
        for (int m = 0; m < 16; ++m) mx = fmaxf(mx, s.attn[r][m][hh]);
        float ex[16], sum = 0.f;
        #pragma unroll
        for (int m = 0; m < 16; ++m) { ex[m] = __expf(s.attn[r][m][hh] - mx); sum += ex[m]; }
        const float inv = 1.f / sum;
        #pragma unroll
        for (int m = 0; m < 16; ++m) s.attn[r][m][hh] = ex[m] * inv;
    }
    __syncthreads();

    // P4: Z[r][h][d] = sum_m attn[r][m][h] * h[nl[r][m]][d]
    {
        const int r = t >> 6;
        const int l = t & 63;
        const int d0 = l * 2;
        float z[8][2];
        #pragma unroll
        for (int hh = 0; hh < 8; ++hh) { z[hh][0] = 0.f; z[hh][1] = 0.f; }
        for (int m = 0; m < 16; ++m) {
            const int hbase = (b * N_ + s.nls[r][m]) * 128;
            const float h0 = P::ld(h, hbase + d0);
            const float h1 = P::ld(h, hbase + d0 + 1);
            #pragma unroll
            for (int hh = 0; hh < 8; ++hh) {
                const float a = s.attn[r][m][hh];
                z[hh][0] += a * h0;
                z[hh][1] += a * h1;
            }
        }
        #pragma unroll
        for (int hh = 0; hh < 8; ++hh) {
            s.Z[r][hh][d0]     = z[hh][0];
            s.Z[r][hh][d0 + 1] = z[hh][1];
        }
    }
    __syncthreads();

    // P5: agg[r][h*128+e] = sum_d Z[r][h][d] * W[h][d][e]
    {
        float acc[4][RPB];
        #pragma unroll
        for (int c = 0; c < 4; ++c)
            #pragma unroll
            for (int r = 0; r < RPB; ++r) acc[c][r] = 0.f;
        #pragma unroll
        for (int c = 0; c < 4; ++c) {
            const int he = t + 256 * c;
            const int hh = he >> 7;
            const int e  = he & 127;
            const int wbase = hh * (D_ * D_) + e;
            for (int d = 0; d < 128; ++d) {
                const float wv = P::ld(W, wbase + d * 128);
                #pragma unroll
                for (int r = 0; r < RPB; ++r) acc[c][r] += s.Z[r][hh][d] * wv;
            }
        }
        #pragma unroll
        for (int c = 0; c < 4; ++c)
            #pragma unroll
            for (int r = 0; r < RPB; ++r) s.agg[r][t + 256 * c] = acc[c][r];
    }
    __syncthreads();

    // P6: yln[r] = agg[r] @ Wo + hs[r]
    {
        const int e    = t & 127;
        const int half = t >> 7;
        float a0 = 0.f, a1 = 0.f;
        for (int k = 0; k < 1024; ++k) {
            const float wv = P::ld(Wo, k * 128 + e);
            a0 += s.agg[half][k] * wv;
            a1 += s.agg[half + 2][k] * wv;
        }
        s.yln[half][e]     = a0 + s.hs[half][e];
        s.yln[half + 2][e] = a1 + s.hs[half + 2][e];
    }
    __syncthreads();

    // P7: LayerNorm1 -> ts
    {
        const int r = t >> 6;
        const int l = t & 63;
        const float x0 = s.yln[r][l];
        const float x1 = s.yln[r][l + 64];
        float sm = x0 + x1, ss = x0 * x0 + x1 * x1;
        #pragma unroll
        for (int off = 32; off > 0; off >>= 1) {
            sm += __shfl_xor(sm, off);
            ss += __shfl_xor(ss, off);
        }
        const float mu   = sm * (1.f / 128.f);
        const float var  = ss * (1.f / 128.f) - mu * mu;
        const float rstd = rsqrtf(var + 1e-5f);
        s.ts[r][l]      = (x0 - mu) * rstd * P::ld(g1, l)      + P::ld(bb1, l);
        s.ts[r][l + 64] = (x1 - mu) * rstd * P::ld(g1, l + 64) + P::ld(bb1, l + 64);
    }
    __syncthreads();

    // P8: us = relu(ts @ w1 + b1)
    {
        float acc[RPB];
        #pragma unroll
        for (int r = 0; r < RPB; ++r) acc[r] = 0.f;
        for (int k = 0; k < 128; ++k) {
            const float wv = P::ld(w1, k * 256 + t);
            #pragma unroll
            for (int r = 0; r < RPB; ++r) acc[r] += s.ts[r][k] * wv;
        }
        const float bias = P::ld(fb1, t);
        #pragma unroll
        for (int r = 0; r < RPB; ++r) s.us[r][t] = fmaxf(acc[r] + bias, 0.f);
    }
    __syncthreads();

    // P9: ys = us @ w2 + b2 + ts
    {
        const int e    = t & 127;
        const int half = t >> 7;
        float a0 = 0.f, a1 = 0.f;
        for (int k = 0; k < 256; ++k) {
            const float wv = P::ld(w2, k * 128 + e);
            a0 += s.us[half][k] * wv;
            a1 += s.us[half + 2][k] * wv;
        }
        const float bias = P::ld(fb2, e);
        s.ys[half][e]     = a0 + bias + s.ts[half][e];
        s.ys[half + 2][e] = a1 + bias + s.ts[half + 2][e];
    }
    __syncthreads();

    // P10: LayerNorm2 -> out
    {
        const int r = t >> 6;
        const int l = t & 63;
        const float x0 = s.ys[r][l];
        const float x1 = s.ys[r][l + 64];
        float sm = x0 + x1, ss = x0 * x0 + x1 * x1;
        #pragma unroll
        for (int off = 32; off > 0; off >>= 1) {
            sm += __shfl_xor(sm, off);
            ss += __shfl_xor(ss, off);
        }
        const float mu   = sm * (1.f / 128.f);
        const float var  = ss * (1.f / 128.f) - mu * mu;
        const float rstd = rsqrtf(var + 1e-5f);
        P::st(out, (bn0 + r) * 128 + l,
              (x0 - mu) * rstd * P::ld(g2, l) + P::ld(bb2, l));
        P::st(out, (bn0 + r) * 128 + l + 64,
              (x1 - mu) * rstd * P::ld(g2, l + 64) + P::ld(bb2, l + 64));
    }
}

// ---------------------------------------------------------------------------
// Dtype-adaptive wrapper: probe h's even bf16 elements. Genuine bf16 inputs
// give normal values; f32-reinterpreted gives random-exponent garbage at the
// low (even) halves -> detect f32 with overwhelming probability.
// ---------------------------------------------------------------------------
__global__ __launch_bounds__(256) void k_gat_fused(
        const void* __restrict__ h,
        const int*  __restrict__ adj,
        const int*  __restrict__ n_list,
        const void* __restrict__ W,
        const void* __restrict__ a_src,
        const void* __restrict__ a_dst,
        const void* __restrict__ Wo,
        const void* __restrict__ g1,
        const void* __restrict__ bb1,
        const void* __restrict__ w1,
        const void* __restrict__ fb1,
        const void* __restrict__ w2,
        const void* __restrict__ fb2,
        const void* __restrict__ g2,
        const void* __restrict__ bb2,
        void* __restrict__ out) {
    __shared__ Smem s;

    bool is_f32 = false;
    const __hip_bfloat16* hb = (const __hip_bfloat16*)h;
    for (int i = 0; i < 128; ++i) {
        const float v = bf2f(hb[2 * i]);       // low halves if buffer is f32
        if (!(fabsf(v) < 1e4f)) is_f32 = true; // catches huge & NaN
    }

    if (is_f32)
        gat_body<true >(s, h, adj, n_list, W, a_src, a_dst, Wo, g1, bb1,
                        w1, fb1, w2, fb2, g2, bb2, out);
    else
        gat_body<false>(s, h, adj, n_list, W, a_src, a_dst, Wo, g1, bb1,
                        w1, fb1, w2, fb2, g2, bb2, out);
}

// ---------------------------------------------------------------------------
extern "C" void kernel_launch(void* const* d_in, const int* in_sizes, int n_in,
                              void* d_out, int out_size, void* d_ws, size_t ws_size,
                              hipStream_t stream) {
    (void)in_sizes; (void)n_in; (void)out_size; (void)d_ws; (void)ws_size;

    k_gat_fused<<<BN_ / RPB, 256, 0, stream>>>(
        d_in[0], (const int*)d_in[1], (const int*)d_in[2], d_in[3], d_in[4],
        d_in[5], d_in[6], d_in[7], d_in[8], d_in[9], d_in[10], d_in[11],
        d_in[12], d_in[13], d_in[14], d_out);
}

// Round 8
// 550.014 us; speedup vs baseline: 1.1718x; 1.1718x over previous
//
#include <hip/hip_runtime.h>
#include <hip/hip_bf16.h>

// Problem constants
#define B_  16
#define N_  512
#define M_  16
#define H_  8
#define D_  128
#define BN_ 8192   // B_*N_
#define RPB 4      // nodes (b,n) per block

static __device__ __forceinline__ float bf2f(__hip_bfloat16 x) { return __bfloat162float(x); }
static __device__ __forceinline__ unsigned short f2bu(float x) {
    __hip_bfloat16 b = __float2bfloat16(x);
    return *reinterpret_cast<unsigned short*>(&b);
}
static __device__ __forceinline__ float bu2f(unsigned short u) {
    return __uint_as_float(((unsigned int)u) << 16);
}

// Load/store policy: interpret float tensors as f32 or bf16.
template <bool F32>
struct Pol {
    static __device__ __forceinline__ float ld(const void* p, int i) {
        if constexpr (F32) return ((const float*)p)[i];
        else               return bf2f(((const __hip_bfloat16*)p)[i]);
    }
    static __device__ __forceinline__ float2 ld2(const void* p, int i) {  // i%2==0
        if constexpr (F32) return *(const float2*)((const float*)p + i);
        else {
            const ushort2 u = *(const ushort2*)((const unsigned short*)p + i);
            return make_float2(bu2f(u.x), bu2f(u.y));
        }
    }
    static __device__ __forceinline__ float4 ld4(const void* p, int i) {  // i%4==0
        if constexpr (F32) return *(const float4*)((const float*)p + i);
        else {
            const ushort4 u = *(const ushort4*)((const unsigned short*)p + i);
            return make_float4(bu2f(u.x), bu2f(u.y), bu2f(u.z), bu2f(u.w));
        }
    }
    static __device__ __forceinline__ void st(void* p, int i, float v) {
        if constexpr (F32) ((float*)p)[i] = v;
        else               ((__hip_bfloat16*)p)[i] = __float2bfloat16(v);
    }
};

struct __align__(16) Smem {
    float hs[RPB][128];                 // off 0
    float wsrc[8][128];                 // off 2048
    float wdst[8][128];                 // off 6144
    float ssrc[RPB][8];                 // off 10240
    float attn[RPB][16][8];             // off 10368
    unsigned short Zb[RPB][8][128];     // off 12416 (bf16 Z)
    float agg[RPB][1024];               // off 20608
    float yln[RPB][128];                // off 36992
    float ts[RPB][128];                 // off 39040
    float us[RPB][256];                 // off 41088
    float ys[RPB][128];                 // off 45184
    int   nls[RPB][16];                 // off 47232
    int   adjs[RPB][16];                // off 47488 -> total 47744 B
};

template <bool F32>
static __device__ __forceinline__ void gat_body(
        Smem& s,
        const void* __restrict__ h,
        const int*  __restrict__ adj,
        const int*  __restrict__ n_list,
        const void* __restrict__ W,
        const void* __restrict__ a_src,
        const void* __restrict__ a_dst,
        const void* __restrict__ Wo,
        const void* __restrict__ g1,
        const void* __restrict__ bb1,
        const void* __restrict__ w1,
        const void* __restrict__ fb1,
        const void* __restrict__ w2,
        const void* __restrict__ fb2,
        const void* __restrict__ g2,
        const void* __restrict__ bb2,
        void* __restrict__ out) {
    using P = Pol<F32>;
    const int t   = threadIdx.x;
    const int bn0 = blockIdx.x * RPB;
    const int b   = bn0 >> 9;             // 512 nodes per batch

    // P0: wsrc[h][d] = sum_e W[h][d][e]*a_src[h][e]; likewise wdst.
    for (int i = t; i < 2048; i += 256) {
        const int which = i >> 10;
        const int hh = (i >> 7) & 7;
        const int d  = i & 127;
        const int wbase = hh * (D_ * D_) + d * 128;
        const void* av = which ? a_dst : a_src;
        float acc = 0.f;
        #pragma unroll 8
        for (int e = 0; e < 128; e += 4) {
            const float4 wv = P::ld4(W, wbase + e);
            const float4 aa = P::ld4(av, hh * 128 + e);
            acc += wv.x * aa.x + wv.y * aa.y + wv.z * aa.z + wv.w * aa.w;
        }
        if (which) s.wdst[hh][d] = acc; else s.wsrc[hh][d] = acc;
    }

    // P1: self rows + neighbor lists
    for (int i = t; i < RPB * 128; i += 256)
        s.hs[i >> 7][i & 127] = P::ld(h, (bn0 + (i >> 7)) * 128 + (i & 127));
    if (t < RPB * 16) {
        const int r = t >> 4, m = t & 15;
        s.nls[r][m]  = n_list[(bn0 + r) * M_ + m] & (N_ - 1);
        s.adjs[r][m] = adj[(bn0 + r) * M_ + m];
    }
    __syncthreads();

    // P2a: s_src[r][h] = hs[r]·wsrc[h]
    if (t < RPB * 8) {
        const int r = t >> 3, hh = t & 7;
        float acc = 0.f;
        #pragma unroll 8
        for (int d = 0; d < 128; ++d) acc += s.hs[r][d] * s.wsrc[hh][d];
        s.ssrc[r][hh] = acc;
    }
    __syncthreads();

    // P2b: scores = leaky(s_src + h[nl]·wdst), then mask
    for (int i = t; i < RPB * 16 * 8; i += 256) {
        const int r  = i >> 7;
        const int m  = (i >> 3) & 15;
        const int hh = i & 7;
        const int hbase = (b * N_ + s.nls[r][m]) * 128;
        float acc = 0.f;
        #pragma unroll 8
        for (int d = 0; d < 128; d += 4) {
            const float4 hv = P::ld4(h, hbase + d);
            const float4 wv = *(const float4*)&s.wdst[hh][d];
            acc += hv.x * wv.x + hv.y * wv.y + hv.z * wv.z + hv.w * wv.w;
        }
        float sc = s.ssrc[r][hh] + acc;
        sc = sc > 0.f ? sc : 0.2f * sc;       // leaky_relu BEFORE mask (ref order)
        if (s.adjs[r][m] == 0) sc = -1e9f;
        s.attn[r][m][hh] = sc;
    }
    __syncthreads();

    // P3: softmax over m
    if (t < RPB * 8) {
        const int r = t >> 3, hh = t & 7;
        float mx = -3.4e38f;
        #pragma unroll
        for (int m = 0; m < 16; ++m) mx = fmaxf(mx, s.attn[r][m][hh]);
        float ex[16], sum = 0.f;
        #pragma unroll
        for (int m = 0; m < 16; ++m) { ex[m] = __expf(s.attn[r][m][hh] - mx); sum += ex[m]; }
        const float inv = 1.f / sum;
        #pragma unroll
        for (int m = 0; m < 16; ++m) s.attn[r][m][hh] = ex[m] * inv;
    }
    __syncthreads();

    // P4: Z[r][h][d] = sum_m attn[r][m][h] * h[nl[r][m]][d]  (bf16 store)
    {
        const int r = t >> 6;
        const int l = t & 63;
        const int d0 = l * 2;
        float z[8][2];
        #pragma unroll
        for (int hh = 0; hh < 8; ++hh) { z[hh][0] = 0.f; z[hh][1] = 0.f; }
        for (int m = 0; m < 16; ++m) {
            const int hbase = (b * N_ + s.nls[r][m]) * 128;
            const float2 hv = P::ld2(h, hbase + d0);
            #pragma unroll
            for (int hh = 0; hh < 8; ++hh) {
                const float a = s.attn[r][m][hh];
                z[hh][0] += a * hv.x;
                z[hh][1] += a * hv.y;
            }
        }
        #pragma unroll
        for (int hh = 0; hh < 8; ++hh) {
            ushort2 uv;
            uv.x = f2bu(z[hh][0]);
            uv.y = f2bu(z[hh][1]);
            *(ushort2*)&s.Zb[r][hh][d0] = uv;
        }
    }
    __syncthreads();

    // P5: agg[r][h*128+e] = sum_d Z[r][h][d] * W[h][d][e]
    {
        float acc[4][RPB];
        #pragma unroll
        for (int c = 0; c < 4; ++c)
            #pragma unroll
            for (int r = 0; r < RPB; ++r) acc[c][r] = 0.f;
        #pragma unroll
        for (int c = 0; c < 4; ++c) {
            const int he = t + 256 * c;
            const int hh = he >> 7;
            const int e  = he & 127;
            const int wbase = hh * (D_ * D_) + e;
            for (int d = 0; d < 128; ++d) {
                const float wv = P::ld(W, wbase + d * 128);
                #pragma unroll
                for (int r = 0; r < RPB; ++r) acc[c][r] += bu2f(s.Zb[r][hh][d]) * wv;
            }
        }
        #pragma unroll
        for (int c = 0; c < 4; ++c)
            #pragma unroll
            for (int r = 0; r < RPB; ++r) s.agg[r][t + 256 * c] = acc[c][r];
    }
    __syncthreads();

    // P6: yln[r] = agg[r] @ Wo + hs[r]
    {
        const int e    = t & 127;
        const int half = t >> 7;
        float a0 = 0.f, a1 = 0.f;
        for (int k0 = 0; k0 < 1024; k0 += 4) {
            float wo[4];
            #pragma unroll
            for (int j = 0; j < 4; ++j) wo[j] = P::ld(Wo, (k0 + j) * 128 + e);
            const float4 g0 = *(const float4*)&s.agg[half][k0];
            const float4 q1 = *(const float4*)&s.agg[half + 2][k0];
            a0 += g0.x * wo[0] + g0.y * wo[1] + g0.z * wo[2] + g0.w * wo[3];
            a1 += q1.x * wo[0] + q1.y * wo[1] + q1.z * wo[2] + q1.w * wo[3];
        }
        s.yln[half][e]     = a0 + s.hs[half][e];
        s.yln[half + 2][e] = a1 + s.hs[half + 2][e];
    }
    __syncthreads();

    // P7: LayerNorm1 -> ts
    {
        const int r = t >> 6;
        const int l = t & 63;
        const float x0 = s.yln[r][l];
        const float x1 = s.yln[r][l + 64];
        float sm = x0 + x1, ss = x0 * x0 + x1 * x1;
        #pragma unroll
        for (int off = 32; off > 0; off >>= 1) {
            sm += __shfl_xor(sm, off);
            ss += __shfl_xor(ss, off);
        }
        const float mu   = sm * (1.f / 128.f);
        const float var  = ss * (1.f / 128.f) - mu * mu;
        const float rstd = rsqrtf(var + 1e-5f);
        s.ts[r][l]      = (x0 - mu) * rstd * P::ld(g1, l)      + P::ld(bb1, l);
        s.ts[r][l + 64] = (x1 - mu) * rstd * P::ld(g1, l + 64) + P::ld(bb1, l + 64);
    }
    __syncthreads();

    // P8: us = relu(ts @ w1 + b1)
    {
        float acc[RPB];
        #pragma unroll
        for (int r = 0; r < RPB; ++r) acc[r] = 0.f;
        for (int k0 = 0; k0 < 128; k0 += 4) {
            float wv[4];
            #pragma unroll
            for (int j = 0; j < 4; ++j) wv[j] = P::ld(w1, (k0 + j) * 256 + t);
            #pragma unroll
            for (int r = 0; r < RPB; ++r) {
                const float4 tv = *(const float4*)&s.ts[r][k0];
                acc[r] += tv.x * wv[0] + tv.y * wv[1] + tv.z * wv[2] + tv.w * wv[3];
            }
        }
        const float bias = P::ld(fb1, t);
        #pragma unroll
        for (int r = 0; r < RPB; ++r) s.us[r][t] = fmaxf(acc[r] + bias, 0.f);
    }
    __syncthreads();

    // P9: ys = us @ w2 + b2 + ts
    {
        const int e    = t & 127;
        const int half = t >> 7;
        float a0 = 0.f, a1 = 0.f;
        for (int k0 = 0; k0 < 256; k0 += 4) {
            float wv[4];
            #pragma unroll
            for (int j = 0; j < 4; ++j) wv[j] = P::ld(w2, (k0 + j) * 128 + e);
            const float4 u0 = *(const float4*)&s.us[half][k0];
            const float4 u1 = *(const float4*)&s.us[half + 2][k0];
            a0 += u0.x * wv[0] + u0.y * wv[1] + u0.z * wv[2] + u0.w * wv[3];
            a1 += u1.x * wv[0] + u1.y * wv[1] + u1.z * wv[2] + u1.w * wv[3];
        }
        const float bias = P::ld(fb2, e);
        s.ys[half][e]     = a0 + bias + s.ts[half][e];
        s.ys[half + 2][e] = a1 + bias + s.ts[half + 2][e];
    }
    __syncthreads();

    // P10: LayerNorm2 -> out
    {
        const int r = t >> 6;
        const int l = t & 63;
        const float x0 = s.ys[r][l];
        const float x1 = s.ys[r][l + 64];
        float sm = x0 + x1, ss = x0 * x0 + x1 * x1;
        #pragma unroll
        for (int off = 32; off > 0; off >>= 1) {
            sm += __shfl_xor(sm, off);
            ss += __shfl_xor(ss, off);
        }
        const float mu   = sm * (1.f / 128.f);
        const float var  = ss * (1.f / 128.f) - mu * mu;
        const float rstd = rsqrtf(var + 1e-5f);
        P::st(out, (bn0 + r) * 128 + l,
              (x0 - mu) * rstd * P::ld(g2, l) + P::ld(bb2, l));
        P::st(out, (bn0 + r) * 128 + l + 64,
              (x1 - mu) * rstd * P::ld(g2, l + 64) + P::ld(bb2, l + 64));
    }
}

// ---------------------------------------------------------------------------
// Dtype-adaptive wrapper (verbatim from the passing round-4 kernel).
// ---------------------------------------------------------------------------
__global__ __launch_bounds__(256) void k_gat_fused(
        const void* __restrict__ h,
        const int*  __restrict__ adj,
        const int*  __restrict__ n_list,
        const void* __restrict__ W,
        const void* __restrict__ a_src,
        const void* __restrict__ a_dst,
        const void* __restrict__ Wo,
        const void* __restrict__ g1,
        const void* __restrict__ bb1,
        const void* __restrict__ w1,
        const void* __restrict__ fb1,
        const void* __restrict__ w2,
        const void* __restrict__ fb2,
        const void* __restrict__ g2,
        const void* __restrict__ bb2,
        void* __restrict__ out) {
    __shared__ Smem s;

    bool is_f32 = false;
    const __hip_bfloat16* hb = (const __hip_bfloat16*)h;
    for (int i = 0; i < 128; ++i) {
        const float v = bf2f(hb[2 * i]);       // low halves if buffer is f32
        if (!(fabsf(v) < 1e4f)) is_f32 = true; // catches huge & NaN
    }

    if (is_f32)
        gat_body<true >(s, h, adj, n_list, W, a_src, a_dst, Wo, g1, bb1,
                        w1, fb1, w2, fb2, g2, bb2, out);
    else
        gat_body<false>(s, h, adj, n_list, W, a_src, a_dst, Wo, g1, bb1,
                        w1, fb1, w2, fb2, g2, bb2, out);
}

// ---------------------------------------------------------------------------
extern "C" void kernel_launch(void* const* d_in, const int* in_sizes, int n_in,
                              void* d_out, int out_size, void* d_ws, size_t ws_size,
                              hipStream_t stream) {
    (void)in_sizes; (void)n_in; (void)out_size; (void)d_ws; (void)ws_size;

    k_gat_fused<<<BN_ / RPB, 256, 0, stream>>>(
        d_in[0], (const int*)d_in[1], (const int*)d_in[2], d_in[3], d_in[4],
        d_in[5], d_in[6], d_in[7], d_in[8], d_in[9], d_in[10], d_in[11],
        d_in[12], d_in[13], d_in[14], d_out);
}

// Round 9
// 299.042 us; speedup vs baseline: 2.1553x; 1.8393x over previous
//
#include <hip/hip_runtime.h>
#include <hip/hip_bf16.h>

// Problem constants
#define B_  16
#define N_  512
#define M_  16
#define H_  8
#define D_  128
#define BN_ 8192   // B_*N_
#define RPB 4      // nodes (b,n) per block

static __device__ __forceinline__ float bf2f(__hip_bfloat16 x) { return __bfloat162float(x); }
static __device__ __forceinline__ unsigned short f2bu(float x) {
    __hip_bfloat16 b = __float2bfloat16(x);
    return *reinterpret_cast<unsigned short*>(&b);
}
static __device__ __forceinline__ float bu2f(unsigned short u) {
    return __uint_as_float(((unsigned int)u) << 16);
}

// Load/store policy: interpret float tensors as f32 or bf16.
template <bool F32>
struct Pol {
    static __device__ __forceinline__ float ld(const void* p, int i) {
        if constexpr (F32) return ((const float*)p)[i];
        else               return bf2f(((const __hip_bfloat16*)p)[i]);
    }
    static __device__ __forceinline__ float2 ld2(const void* p, int i) {  // i%2==0
        if constexpr (F32) return *(const float2*)((const float*)p + i);
        else {
            const ushort2 u = *(const ushort2*)((const unsigned short*)p + i);
            return make_float2(bu2f(u.x), bu2f(u.y));
        }
    }
    static __device__ __forceinline__ float4 ld4(const void* p, int i) {  // i%4==0
        if constexpr (F32) return *(const float4*)((const float*)p + i);
        else {
            const ushort4 u = *(const ushort4*)((const unsigned short*)p + i);
            return make_float4(bu2f(u.x), bu2f(u.y), bu2f(u.z), bu2f(u.w));
        }
    }
    static __device__ __forceinline__ void st(void* p, int i, float v) {
        if constexpr (F32) ((float*)p)[i] = v;
        else               ((__hip_bfloat16*)p)[i] = __float2bfloat16(v);
    }
};

// Dtype probe (verbatim r4/r8 logic): f32 buffers read as bf16 at even index
// give random-exponent garbage; genuine bf16 stays small.
static __device__ __forceinline__ bool probe_is_f32(const void* h) {
    bool is_f32 = false;
    const __hip_bfloat16* hb = (const __hip_bfloat16*)h;
    for (int i = 0; i < 128; ++i) {
        const float v = bf2f(hb[2 * i]);
        if (!(fabsf(v) < 1e4f)) is_f32 = true;
    }
    return is_f32;
}

// ---------------------------------------------------------------------------
// K0a: wsrc[h][d] = sum_e W[h][d][e]*a_src[h][e]; likewise wdst.  grid 8.
// ---------------------------------------------------------------------------
template <bool F32>
static __device__ __forceinline__ void k0a_body(const void* __restrict__ W,
                                                const void* __restrict__ a_src,
                                                const void* __restrict__ a_dst,
                                                float* __restrict__ wsrc,
                                                float* __restrict__ wdst) {
    using P = Pol<F32>;
    const int hh = blockIdx.x;
    const int t  = threadIdx.x;
    const int which = t >> 7;
    const int d  = t & 127;
    const int wbase = hh * (D_ * D_) + d * 128;
    const void* av = which ? a_dst : a_src;
    float acc = 0.f;
    #pragma unroll 8
    for (int e = 0; e < 128; e += 4) {
        const float4 wv = P::ld4(W, wbase + e);
        const float4 aa = P::ld4(av, hh * 128 + e);
        acc += wv.x * aa.x + wv.y * aa.y + wv.z * aa.z + wv.w * aa.w;
    }
    (which ? wdst : wsrc)[hh * 128 + d] = acc;
}

__global__ __launch_bounds__(256) void k0a(const void* __restrict__ W,
                                           const void* __restrict__ a_src,
                                           const void* __restrict__ a_dst,
                                           const void* __restrict__ h,
                                           float* __restrict__ wsrc,
                                           float* __restrict__ wdst) {
    if (probe_is_f32(h)) k0a_body<true >(W, a_src, a_dst, wsrc, wdst);
    else                 k0a_body<false>(W, a_src, a_dst, wsrc, wdst);
}

// ---------------------------------------------------------------------------
// K1: per-node s_src/s_dst. One wave per node; grid BN_/4 x 256.
// ---------------------------------------------------------------------------
template <bool F32>
static __device__ __forceinline__ void k1_body(const void* __restrict__ h,
                                               const float* __restrict__ wsrc,
                                               const float* __restrict__ wdst,
                                               float* __restrict__ ssrc,
                                               float* __restrict__ sdst) {
    using P = Pol<F32>;
    const int w  = threadIdx.x >> 6;
    const int l  = threadIdx.x & 63;
    const int bn = blockIdx.x * 4 + w;
    const float x0 = P::ld(h, bn * 128 + l);
    const float x1 = P::ld(h, bn * 128 + 64 + l);
    for (int hh = 0; hh < 8; ++hh) {
        float ps = x0 * wsrc[hh * 128 + l] + x1 * wsrc[hh * 128 + 64 + l];
        float pd = x0 * wdst[hh * 128 + l] + x1 * wdst[hh * 128 + 64 + l];
        #pragma unroll
        for (int off = 32; off > 0; off >>= 1) {
            ps += __shfl_xor(ps, off);
            pd += __shfl_xor(pd, off);
        }
        if (l == 0) {
            ssrc[bn * 8 + hh] = ps;
            sdst[bn * 8 + hh] = pd;
        }
    }
}

__global__ __launch_bounds__(256) void k1(const void* __restrict__ h,
                                          const float* __restrict__ wsrc,
                                          const float* __restrict__ wdst,
                                          float* __restrict__ ssrc,
                                          float* __restrict__ sdst) {
    if (probe_is_f32(h)) k1_body<true >(h, wsrc, wdst, ssrc, sdst);
    else                 k1_body<false>(h, wsrc, wdst, ssrc, sdst);
}

// ---------------------------------------------------------------------------
// Main fused kernel: r8 verbatim except P0/P2a removed (ssrc/sdst gathered
// from k1's output) and wsrc/wdst dropped from LDS (39.6 KB -> 4 blocks/CU).
// ---------------------------------------------------------------------------
struct __align__(16) Smem {
    float hs[RPB][128];
    float ssrc[RPB][8];
    float attn[RPB][16][8];
    unsigned short Zb[RPB][8][128];     // bf16 Z
    float agg[RPB][1024];
    float yln[RPB][128];
    float ts[RPB][128];
    float us[RPB][256];
    float ys[RPB][128];
    int   nls[RPB][16];
    int   adjs[RPB][16];
};

template <bool F32>
static __device__ __forceinline__ void gat_body(
        Smem& s,
        const void* __restrict__ h,
        const int*  __restrict__ adj,
        const int*  __restrict__ n_list,
        const float* __restrict__ ssrc_g,
        const float* __restrict__ sdst_g,
        const void* __restrict__ W,
        const void* __restrict__ Wo,
        const void* __restrict__ g1,
        const void* __restrict__ bb1,
        const void* __restrict__ w1,
        const void* __restrict__ fb1,
        const void* __restrict__ w2,
        const void* __restrict__ fb2,
        const void* __restrict__ g2,
        const void* __restrict__ bb2,
        void* __restrict__ out) {
    using P = Pol<F32>;
    const int t   = threadIdx.x;
    const int bn0 = blockIdx.x * RPB;
    const int b   = bn0 >> 9;             // 512 nodes per batch

    // P1: self rows + neighbor lists + gathered ssrc
    for (int i = t; i < RPB * 128; i += 256)
        s.hs[i >> 7][i & 127] = P::ld(h, (bn0 + (i >> 7)) * 128 + (i & 127));
    if (t < RPB * 16) {
        const int r = t >> 4, m = t & 15;
        s.nls[r][m]  = n_list[(bn0 + r) * M_ + m] & (N_ - 1);
        s.adjs[r][m] = adj[(bn0 + r) * M_ + m];
    }
    if (t >= 128 && t < 128 + RPB * 8) {
        const int i = t - 128;
        s.ssrc[i >> 3][i & 7] = ssrc_g[(bn0 + (i >> 3)) * 8 + (i & 7)];
    }
    __syncthreads();

    // P2b: scores = leaky(s_src + s_dst[nl]), then mask  (s_dst gathered)
    for (int i = t; i < RPB * 16 * 8; i += 256) {
        const int r  = i >> 7;
        const int m  = (i >> 3) & 15;
        const int hh = i & 7;
        float sc = s.ssrc[r][hh] + sdst_g[(b * N_ + s.nls[r][m]) * 8 + hh];
        sc = sc > 0.f ? sc : 0.2f * sc;       // leaky_relu BEFORE mask (ref order)
        if (s.adjs[r][m] == 0) sc = -1e9f;
        s.attn[r][m][hh] = sc;
    }
    __syncthreads();

    // P3: softmax over m
    if (t < RPB * 8) {
        const int r = t >> 3, hh = t & 7;
        float mx = -3.4e38f;
        #pragma unroll
        for (int m = 0; m < 16; ++m) mx = fmaxf(mx, s.attn[r][m][hh]);
        float ex[16], sum = 0.f;
        #pragma unroll
        for (int m = 0; m < 16; ++m) { ex[m] = __expf(s.attn[r][m][hh] - mx); sum += ex[m]; }
        const float inv = 1.f / sum;
        #pragma unroll
        for (int m = 0; m < 16; ++m) s.attn[r][m][hh] = ex[m] * inv;
    }
    __syncthreads();

    // P4: Z[r][h][d] = sum_m attn[r][m][h] * h[nl[r][m]][d]  (bf16 store)
    {
        const int r = t >> 6;
        const int l = t & 63;
        const int d0 = l * 2;
        float z[8][2];
        #pragma unroll
        for (int hh = 0; hh < 8; ++hh) { z[hh][0] = 0.f; z[hh][1] = 0.f; }
        for (int m = 0; m < 16; ++m) {
            const int hbase = (b * N_ + s.nls[r][m]) * 128;
            const float2 hv = P::ld2(h, hbase + d0);
            #pragma unroll
            for (int hh = 0; hh < 8; ++hh) {
                const float a = s.attn[r][m][hh];
                z[hh][0] += a * hv.x;
                z[hh][1] += a * hv.y;
            }
        }
        #pragma unroll
        for (int hh = 0; hh < 8; ++hh) {
            ushort2 uv;
            uv.x = f2bu(z[hh][0]);
            uv.y = f2bu(z[hh][1]);
            *(ushort2*)&s.Zb[r][hh][d0] = uv;
        }
    }
    __syncthreads();

    // P5: agg[r][h*128+e] = sum_d Z[r][h][d] * W[h][d][e]
    {
        float acc[4][RPB];
        #pragma unroll
        for (int c = 0; c < 4; ++c)
            #pragma unroll
            for (int r = 0; r < RPB; ++r) acc[c][r] = 0.f;
        #pragma unroll
        for (int c = 0; c < 4; ++c) {
            const int he = t + 256 * c;
            const int hh = he >> 7;
            const int e  = he & 127;
            const int wbase = hh * (D_ * D_) + e;
            for (int d = 0; d < 128; ++d) {
                const float wv = P::ld(W, wbase + d * 128);
                #pragma unroll
                for (int r = 0; r < RPB; ++r) acc[c][r] += bu2f(s.Zb[r][hh][d]) * wv;
            }
        }
        #pragma unroll
        for (int c = 0; c < 4; ++c)
            #pragma unroll
            for (int r = 0; r < RPB; ++r) s.agg[r][t + 256 * c] = acc[c][r];
    }
    __syncthreads();

    // P6: yln[r] = agg[r] @ Wo + hs[r]
    {
        const int e    = t & 127;
        const int half = t >> 7;
        float a0 = 0.f, a1 = 0.f;
        for (int k0 = 0; k0 < 1024; k0 += 4) {
            float wo[4];
            #pragma unroll
            for (int j = 0; j < 4; ++j) wo[j] = P::ld(Wo, (k0 + j) * 128 + e);
            const float4 g0 = *(const float4*)&s.agg[half][k0];
            const float4 q1 = *(const float4*)&s.agg[half + 2][k0];
            a0 += g0.x * wo[0] + g0.y * wo[1] + g0.z * wo[2] + g0.w * wo[3];
            a1 += q1.x * wo[0] + q1.y * wo[1] + q1.z * wo[2] + q1.w * wo[3];
        }
        s.yln[half][e]     = a0 + s.hs[half][e];
        s.yln[half + 2][e] = a1 + s.hs[half + 2][e];
    }
    __syncthreads();

    // P7: LayerNorm1 -> ts
    {
        const int r = t >> 6;
        const int l = t & 63;
        const float x0 = s.yln[r][l];
        const float x1 = s.yln[r][l + 64];
        float sm = x0 + x1, ss = x0 * x0 + x1 * x1;
        #pragma unroll
        for (int off = 32; off > 0; off >>= 1) {
            sm += __shfl_xor(sm, off);
            ss += __shfl_xor(ss, off);
        }
        const float mu   = sm * (1.f / 128.f);
        const float var  = ss * (1.f / 128.f) - mu * mu;
        const float rstd = rsqrtf(var + 1e-5f);
        s.ts[r][l]      = (x0 - mu) * rstd * P::ld(g1, l)      + P::ld(bb1, l);
        s.ts[r][l + 64] = (x1 - mu) * rstd * P::ld(g1, l + 64) + P::ld(bb1, l + 64);
    }
    __syncthreads();

    // P8: us = relu(ts @ w1 + b1)
    {
        float acc[RPB];
        #pragma unroll
        for (int r = 0; r < RPB; ++r) acc[r] = 0.f;
        for (int k0 = 0; k0 < 128; k0 += 4) {
            float wv[4];
            #pragma unroll
            for (int j = 0; j < 4; ++j) wv[j] = P::ld(w1, (k0 + j) * 256 + t);
            #pragma unroll
            for (int r = 0; r < RPB; ++r) {
                const float4 tv = *(const float4*)&s.ts[r][k0];
                acc[r] += tv.x * wv[0] + tv.y * wv[1] + tv.z * wv[2] + tv.w * wv[3];
            }
        }
        const float bias = P::ld(fb1, t);
        #pragma unroll
        for (int r = 0; r < RPB; ++r) s.us[r][t] = fmaxf(acc[r] + bias, 0.f);
    }
    __syncthreads();

    // P9: ys = us @ w2 + b2 + ts
    {
        const int e    = t & 127;
        const int half = t >> 7;
        float a0 = 0.f, a1 = 0.f;
        for (int k0 = 0; k0 < 256; k0 += 4) {
            float wv[4];
            #pragma unroll
            for (int j = 0; j < 4; ++j) wv[j] = P::ld(w2, (k0 + j) * 128 + e);
            const float4 u0 = *(const float4*)&s.us[half][k0];
            const float4 u1 = *(const float4*)&s.us[half + 2][k0];
            a0 += u0.x * wv[0] + u0.y * wv[1] + u0.z * wv[2] + u0.w * wv[3];
            a1 += u1.x * wv[0] + u1.y * wv[1] + u1.z * wv[2] + u1.w * wv[3];
        }
        const float bias = P::ld(fb2, e);
        s.ys[half][e]     = a0 + bias + s.ts[half][e];
        s.ys[half + 2][e] = a1 + bias + s.ts[half + 2][e];
    }
    __syncthreads();

    // P10: LayerNorm2 -> out
    {
        const int r = t >> 6;
        const int l = t & 63;
        const float x0 = s.ys[r][l];
        const float x1 = s.ys[r][l + 64];
        float sm = x0 + x1, ss = x0 * x0 + x1 * x1;
        #pragma unroll
        for (int off = 32; off > 0; off >>= 1) {
            sm += __shfl_xor(sm, off);
            ss += __shfl_xor(ss, off);
        }
        const float mu   = sm * (1.f / 128.f);
        const float var  = ss * (1.f / 128.f) - mu * mu;
        const float rstd = rsqrtf(var + 1e-5f);
        P::st(out, (bn0 + r) * 128 + l,
              (x0 - mu) * rstd * P::ld(g2, l) + P::ld(bb2, l));
        P::st(out, (bn0 + r) * 128 + l + 64,
              (x1 - mu) * rstd * P::ld(g2, l + 64) + P::ld(bb2, l + 64));
    }
}

__global__ __launch_bounds__(256) void k_gat_fused(
        const void* __restrict__ h,
        const int*  __restrict__ adj,
        const int*  __restrict__ n_list,
        const float* __restrict__ ssrc_g,
        const float* __restrict__ sdst_g,
        const void* __restrict__ W,
        const void* __restrict__ Wo,
        const void* __restrict__ g1,
        const void* __restrict__ bb1,
        const void* __restrict__ w1,
        const void* __restrict__ fb1,
        const void* __restrict__ w2,
        const void* __restrict__ fb2,
        const void* __restrict__ g2,
        const void* __restrict__ bb2,
        void* __restrict__ out) {
    __shared__ Smem s;
    if (probe_is_f32(h))
        gat_body<true >(s, h, adj, n_list, ssrc_g, sdst_g, W, Wo, g1, bb1,
                        w1, fb1, w2, fb2, g2, bb2, out);
    else
        gat_body<false>(s, h, adj, n_list, ssrc_g, sdst_g, W, Wo, g1, bb1,
                        w1, fb1, w2, fb2, g2, bb2, out);
}

// ---------------------------------------------------------------------------
extern "C" void kernel_launch(void* const* d_in, const int* in_sizes, int n_in,
                              void* d_out, int out_size, void* d_ws, size_t ws_size,
                              hipStream_t stream) {
    (void)in_sizes; (void)n_in; (void)out_size; (void)ws_size;

    // ws layout (float offsets): wsrc 0 | wdst 1024 | ssrc 2048 | sdst 67584
    // total 133120 floats = 532480 bytes
    float* ws   = (float*)d_ws;
    float* wsrc = ws;
    float* wdst = ws + 1024;
    float* ssrc = ws + 2048;
    float* sdst = ws + 67584;

    k0a<<<8,        256, 0, stream>>>(d_in[3], d_in[4], d_in[5], d_in[0], wsrc, wdst);
    k1 <<<BN_ / 4,  256, 0, stream>>>(d_in[0], wsrc, wdst, ssrc, sdst);
    k_gat_fused<<<BN_ / RPB, 256, 0, stream>>>(
        d_in[0], (const int*)d_in[1], (const int*)d_in[2], ssrc, sdst,
        d_in[3], d_in[6], d_in[7], d_in[8], d_in[9], d_in[10], d_in[11],
        d_in[12], d_in[13], d_in[14], d_out);
}